// Round 1
// baseline (11990.614 us; speedup 1.0000x reference)
//
#include <hip/hip_runtime.h>
#include <cstddef>

#define Hd 51
#define Td 2048
#define BBd 4
#define NT 704
#define NBLK 256

__device__ __forceinline__ float fast_rcp(float x) {
#if __has_builtin(__builtin_amdgcn_rcpf)
    return __builtin_amdgcn_rcpf(x);
#else
    return 1.0f / x;
#endif
}

// ag=1,bg=0 -> sigmoid(a); ag=2,bg=-1 -> tanh(a) (tanh(a)=2*sigmoid(2a)-1)
__device__ __forceinline__ float gate_act(float a, float ag, float bg) {
    float e = __expf(-a * ag);
    float s = fast_rcp(1.0f + e);
    return fmaf(s, ag, bg);
}

__device__ __forceinline__ float tanh_fast(float x) {
    float e = __expf(-2.0f * fabsf(x));
    float t = (1.0f - e) * fast_rcp(1.0f + e);
    return copysignf(t, x);
}

// Thread roles within the 704-thread block (11 waves):
//   tid [0,204)    : layer-0 gate rows (row j = tid), 2+51 MACs
//   tid [204,212)  : output head: (col = (tid-204)>>2, b = (tid-204)&3)
//   tid [212,220)  : x prefetch: (feat = (tid-212)>>2, b = (tid-212)&3)
//   tid [256,664)  : heavy gate rows: hr=tid-256, layer = 1+hr/204, row = hr%204
//   rest           : idle (barrier only)
// Wave->SIMD (i%4): S0..S2 = {L0, heavy, heavy} ~2810cyc, S3 = {mixed, heavy}.
__global__ __launch_bounds__(NT, 3)
void lstm3_kernel(const float* __restrict__ g_input,
                  const float* __restrict__ g_time,
                  const float* __restrict__ Wih0, const float* __restrict__ Whh0,
                  const float* __restrict__ bih0, const float* __restrict__ bhh0,
                  const float* __restrict__ Wih1, const float* __restrict__ Whh1,
                  const float* __restrict__ bih1, const float* __restrict__ bhh1,
                  const float* __restrict__ Wih2, const float* __restrict__ Whh2,
                  const float* __restrict__ bih2, const float* __restrict__ bhh2,
                  const float* __restrict__ Wlin, const float* __restrict__ blin,
                  float* __restrict__ g_out)
{
    __shared__ float sh_h[3][2][Hd][BBd];   // double-buffered hidden states
    __shared__ float sh_g[3][4 * Hd][BBd];  // activated gates (i,f,g,o rows)
    __shared__ float sh_x[2][2][BBd];       // double-buffered x (input,time)

    const int tid = threadIdx.x;
    const int b0 = blockIdx.x * BBd;

    int role = 3;          // 0=gate-row, 1=out-head, 2=prefetch, 3=idle
    int lay = 0, row = 0;
    if (tid < 204)                      { role = 0; lay = 0; row = tid; }
    else if (tid < 212)                 { role = 1; }
    else if (tid < 220)                 { role = 2; }
    else if (tid >= 256 && tid < 664)   { role = 0; int hr = tid - 256; lay = 1 + hr / 204; row = hr % 204; }

    const int o_idx  = tid - 204;
    const int o_col  = (o_idx >> 2) & 1;
    const int o_b    = o_idx & 3;
    const int p_idx  = tid - 212;
    const int p_feat = (p_idx >> 2) & 1;
    const int p_b    = p_idx & 3;

    float wih[Hd];
    float whh[Hd];
    float bias = 0.0f;

    if (role == 0) {
        const float* Wih = (lay == 0) ? Wih0 : ((lay == 1) ? Wih1 : Wih2);
        const float* Whh = (lay == 0) ? Whh0 : ((lay == 1) ? Whh1 : Whh2);
        const float* bih = (lay == 0) ? bih0 : ((lay == 1) ? bih1 : bih2);
        const float* bhh = (lay == 0) ? bhh0 : ((lay == 1) ? bhh1 : bhh2);
        bias = bih[row] + bhh[row];
        #pragma unroll
        for (int k = 0; k < Hd; ++k) whh[k] = Whh[row * Hd + k];
        if (lay == 0) {
            wih[0] = Wih[row * 2 + 0];
            wih[1] = Wih[row * 2 + 1];
        } else {
            #pragma unroll
            for (int k = 0; k < Hd; ++k) wih[k] = Wih[row * Hd + k];
        }
    } else if (role == 1) {
        #pragma unroll
        for (int k = 0; k < Hd; ++k) whh[k] = Wlin[o_col * Hd + k];
        bias = blin[o_col];
    }

    // gate nonlinearity params: rows [2H,3H) are 'g' -> tanh, else sigmoid
    const bool  isg = (row >= 2 * Hd) && (row < 3 * Hd);
    const float ag  = isg ? 2.0f : 1.0f;
    const float bg  = isg ? -1.0f : 0.0f;

    // phase-2 mapping: tid < 612 -> (layer, elem, batch); c lives here
    const int p2l = tid / 204;
    const int p2r = tid % 204;
    const int p2e = p2r >> 2;
    const int p2b = p2r & 3;
    float c_state = 0.0f;

    // zero both h buffers (initial state, and pre-first-write reads)
    for (int i = tid; i < 3 * 2 * Hd * BBd; i += NT) ((float*)sh_h)[i] = 0.0f;

    // prologue: x(t=0) -> sh_x[1]  (rb at it=0 is 1)
    if (role == 2) {
        const float* src = (p_feat == 0) ? g_input : g_time;
        sh_x[1][p_feat][p_b] = src[(size_t)(b0 + p_b) * Td];
    }
    __syncthreads();

    const float* hin_base  = (role == 0 && lay > 0) ? &sh_h[lay - 1][0][0][0] : (const float*)&sh_h[0][0][0][0];
    const float* hown_base = &sh_h[lay][0][0][0];

    for (int it = 0; it < Td + 3; ++it) {
        const int rb = (it & 1) ^ 1;
        const int wb = it & 1;

        // prefetch next x into register (written to LDS after barrier 1)
        float pfv = 0.0f;
        if (role == 2 && (it + 1) < Td) {
            const float* src = (p_feat == 0) ? g_input : g_time;
            pfv = src[(size_t)(b0 + p_b) * Td + (it + 1)];
        }

        if (role == 0) {
            const int tl = it - lay;
            if (tl >= 0 && tl < Td) {
                float a0 = bias, a1 = bias, a2 = bias, a3 = bias;
                if (lay == 0) {
                    const float4 x0 = *(const float4*)&sh_x[rb][0][0];
                    const float4 x1 = *(const float4*)&sh_x[rb][1][0];
                    a0 = fmaf(wih[0], x0.x, a0); a1 = fmaf(wih[0], x0.y, a1);
                    a2 = fmaf(wih[0], x0.z, a2); a3 = fmaf(wih[0], x0.w, a3);
                    a0 = fmaf(wih[1], x1.x, a0); a1 = fmaf(wih[1], x1.y, a1);
                    a2 = fmaf(wih[1], x1.z, a2); a3 = fmaf(wih[1], x1.w, a3);
                } else {
                    const float* hin = hin_base + rb * (Hd * BBd);
                    #pragma unroll
                    for (int k = 0; k < Hd; ++k) {
                        const float4 hv = *(const float4*)(hin + k * BBd);
                        a0 = fmaf(wih[k], hv.x, a0); a1 = fmaf(wih[k], hv.y, a1);
                        a2 = fmaf(wih[k], hv.z, a2); a3 = fmaf(wih[k], hv.w, a3);
                    }
                }
                {
                    const float* hw = hown_base + rb * (Hd * BBd);
                    #pragma unroll
                    for (int k = 0; k < Hd; ++k) {
                        const float4 hv = *(const float4*)(hw + k * BBd);
                        a0 = fmaf(whh[k], hv.x, a0); a1 = fmaf(whh[k], hv.y, a1);
                        a2 = fmaf(whh[k], hv.z, a2); a3 = fmaf(whh[k], hv.w, a3);
                    }
                }
                float4 gv;
                gv.x = gate_act(a0, ag, bg);
                gv.y = gate_act(a1, ag, bg);
                gv.z = gate_act(a2, ag, bg);
                gv.w = gate_act(a3, ag, bg);
                *(float4*)&sh_g[lay][row][0] = gv;
            }
        } else if (role == 1) {
            const int to = it - 3;
            if (to >= 0 && to < Td) {
                float a = bias;
                #pragma unroll
                for (int k = 0; k < Hd; ++k)
                    a = fmaf(whh[k], sh_h[2][rb][k][o_b], a);
                if (o_col == 1) {
                    // softplus with the reference's inf guard
                    a = (a > 30.0f) ? a : __logf(1.0f + __expf(a));
                }
                g_out[((size_t)(b0 + o_b) * Td + to) * 2 + o_col] = a;
            }
        }

        __syncthreads();   // gates visible

        if (tid < 612) {
            const int t2 = it - p2l;
            if (t2 >= 0 && t2 < Td) {
                const float gi = sh_g[p2l][p2e][p2b];
                const float gf = sh_g[p2l][Hd + p2e][p2b];
                const float gg = sh_g[p2l][2 * Hd + p2e][p2b];
                const float go = sh_g[p2l][3 * Hd + p2e][p2b];
                c_state = fmaf(gf, c_state, gi * gg);
                sh_h[p2l][wb][p2e][p2b] = go * tanh_fast(c_state);
            }
        }
        if (role == 2 && (it + 1) < Td) {
            sh_x[wb][p_feat][p_b] = pfv;
        }
        __syncthreads();   // h / x visible for next iteration
    }
}

extern "C" void kernel_launch(void* const* d_in, const int* in_sizes, int n_in,
                              void* d_out, int out_size, void* d_ws, size_t ws_size,
                              hipStream_t stream) {
    const float* input = (const float*)d_in[0];
    const float* timei = (const float*)d_in[1];
    const float* Wih0  = (const float*)d_in[2];
    const float* Whh0  = (const float*)d_in[3];
    const float* bih0  = (const float*)d_in[4];
    const float* bhh0  = (const float*)d_in[5];
    const float* Wih1  = (const float*)d_in[6];
    const float* Whh1  = (const float*)d_in[7];
    const float* bih1  = (const float*)d_in[8];
    const float* bhh1  = (const float*)d_in[9];
    const float* Wih2  = (const float*)d_in[10];
    const float* Whh2  = (const float*)d_in[11];
    const float* bih2  = (const float*)d_in[12];
    const float* bhh2  = (const float*)d_in[13];
    const float* Wlin  = (const float*)d_in[14];
    const float* blin  = (const float*)d_in[15];
    float* out = (float*)d_out;

    lstm3_kernel<<<dim3(NBLK), dim3(NT), 0, stream>>>(
        input, timei,
        Wih0, Whh0, bih0, bhh0,
        Wih1, Whh1, bih1, bhh1,
        Wih2, Whh2, bih2, bhh2,
        Wlin, blin, out);
}